// Round 6
// baseline (762.082 us; speedup 1.0000x reference)
//
#include <hip/hip_runtime.h>

// B=8 S=1024 D=1024 H=16 DK=64 F=4096 -- fp32 containers (bf16-valued), detected per-tensor
#define Bq 8
#define Sq 1024
#define Dq 1024
#define Hq 16
#define DKq 64
#define Fq 4096
#define TOK (Bq*Sq)   // 8192

typedef unsigned short u16;
typedef unsigned int u32;
typedef __bf16 bf16x8 __attribute__((ext_vector_type(8)));
typedef float  f32x4  __attribute__((ext_vector_type(4)));

__device__ __forceinline__ float bf2f(u16 u) {
  u32 x = ((u32)u) << 16;
  float f; __builtin_memcpy(&f, &x, 4); return f;
}
__device__ __forceinline__ u16 f2bf(float f) {
  u32 u; __builtin_memcpy(&u, &f, 4);
  u += 0x7fffu + ((u >> 16) & 1u);
  return (u16)(u >> 16);
}
// async global->LDS, 16B/lane; LDS dest = wave-uniform base + lane*16
__device__ __forceinline__ void async16(const u16* g, u16* l) {
  __builtin_amdgcn_global_load_lds(
      (__attribute__((address_space(1))) void*)(g),
      (__attribute__((address_space(3))) void*)(l), 16, 0, 0);
}
__device__ __forceinline__ u16 load_in(const void* p, long idx, u32 fp32) {
  return fp32 ? f2bf(((const float*)p)[idx]) : ((const u16*)p)[idx];
}

// ---------------- dtype detection: one launch, 17 blocks ----------------
struct InTab { const void* p[17]; int n[17]; };

__global__ void detect_all(InTab tab, u32* flags) {
  __shared__ int sh[3][256];
  int bi = blockIdx.x;
  const u16* buf = (const u16*)tab.p[bi];
  long n = tab.n[bi];
  long m = n < 65536 ? n : 65536;
  int t = threadIdx.x;
  int nanpat = 0, evz = 0, oddnz = 0;
  for (long i = t; i < m; i += 256) {
    u16 v = buf[i];
    if ((v & 0x7F80u) == 0x7F80u) nanpat++;
    if ((i & 1) == 0) { if (v == 0) evz++; }
    else { if (v != 0) oddnz++; }
  }
  sh[0][t] = nanpat; sh[1][t] = evz; sh[2][t] = oddnz;
  __syncthreads();
  for (int s = 128; s > 0; s >>= 1) {
    if (t < s) { sh[0][t] += sh[0][t+s]; sh[1][t] += sh[1][t+s]; sh[2][t] += sh[2][t+s]; }
    __syncthreads();
  }
  if (t == 0) {
    long half = m / 2;
    bool fp32 = (sh[0][0] > 8) ||
                (sh[1][0] > (half * 9) / 10 && sh[2][0] > (half * 9) / 10);
    flags[bi] = fp32 ? 1u : 0u;
  }
}

__global__ void diag_ws_too_small(u16* out, float code) { out[0] = f2bf(code); }

__global__ void diag_mixed(const u32* flags, void* out) {
  u32 a = flags[0];
  if (flags[1] != a || flags[7] != a || flags[11] != a || flags[13] != a) {
    if (a) ((float*)out)[0] = 3000.0f;
    else ((u16*)out)[0] = f2bf(3000.0f);
  }
}

// ---------------- LDS-tiled transpose pack: in[Z][R][C] -> out u16 [Z][C][R] ----
// grid (R/64, C/64, Z), block (64,4)
__global__ __launch_bounds__(256) void transpose_pack(const void* __restrict__ in,
                                                      u16* __restrict__ out,
                                                      long zsi, long zso, int R, int C,
                                                      const u32* __restrict__ flag) {
  u32 f = *flag;
  __shared__ u16 tile[64][65];
  int tx = threadIdx.x, ty = threadIdx.y;
  int r0 = blockIdx.x * 64, c0 = blockIdx.y * 64;
  long zin = (long)blockIdx.z * zsi, zout = (long)blockIdx.z * zso;
#pragma unroll
  for (int it = 0; it < 16; it++) {
    int row = it * 4 + ty;
    tile[row][tx] = load_in(in, zin + (long)(r0 + row) * C + (c0 + tx), f);
  }
  __syncthreads();
#pragma unroll
  for (int it = 0; it < 16; it++) {
    int cc = it * 4 + ty;
    out[zout + (long)(c0 + cc) * R + r0 + tx] = tile[tx][cc];
  }
}

// ---------------- merged small-vector cvt ----------------
struct CvtTab { const void* p[10]; int flagidx[10]; int dstoff[10]; int n[10]; };
__global__ void cvt_small(CvtTab tab, u16* __restrict__ dst, const u32* __restrict__ flags) {
  int e = blockIdx.x;
  u32 f = flags[tab.flagidx[e]];
  const void* p = tab.p[e];
  int n = tab.n[e], o = tab.dstoff[e];
  for (int i = threadIdx.x; i < n; i += 256) dst[o + i] = load_in(p, i, f);
}

// ---------------- vectorized src cvt (8 elems/thread) ----------------
__global__ __launch_bounds__(256) void cvt_src(const void* __restrict__ in,
                                               u16* __restrict__ out,
                                               const u32* __restrict__ flag) {
  u32 f = *flag;
  long i8 = ((long)blockIdx.x * 256 + threadIdx.x) * 8;
  if (f) {
    const float4* f4 = (const float4*)((const float*)in + i8);
    float4 a = f4[0], b = f4[1];
    u16 v[8] = {f2bf(a.x), f2bf(a.y), f2bf(a.z), f2bf(a.w),
                f2bf(b.x), f2bf(b.y), f2bf(b.z), f2bf(b.w)};
    *(uint4*)(out + i8) = *(const uint4*)v;
  } else {
    *(uint4*)(out + i8) = *(const uint4*)((const u16*)in + i8);
  }
}

// ---------------- GEMM: C[M,N] = A[M,K] @ Bt[N,K]^T + bias, optional ReLU --------
// 128x128 tile, BK=32, 4 waves each 64x64, 16x16x32 bf16 MFMA, global_load_lds staging
__global__ __launch_bounds__(256) void gemm_bt(const u16* __restrict__ A,
                                               const u16* __restrict__ Bt,
                                               const u16* __restrict__ bias,
                                               u16* __restrict__ C,
                                               int M, int N, int K, int act) {
  __shared__ alignas(16) u16 sA[128 * 32];
  __shared__ alignas(16) u16 sB[128 * 32];
  const int tid = threadIdx.x;
  const int wv = tid >> 6, lane = tid & 63;
  const int m16 = lane & 15, quad = lane >> 4;
  const long bm = (long)blockIdx.x * 128;
  const long bn = (long)blockIdx.y * 128;
  const int wm = (wv >> 1) * 64, wn = (wv & 1) * 64;

  f32x4 acc[4][4];
#pragma unroll
  for (int i = 0; i < 4; i++)
#pragma unroll
    for (int j = 0; j < 4; j++) acc[i][j] = (f32x4){0.f, 0.f, 0.f, 0.f};

  // staging: thread t covers 8 contiguous bf16; tile image row-major [128][32]
  const int row_s = tid >> 2;          // 0..63
  const int col_s = (tid & 3) * 8;
  const u16* gA0 = A + (bm + row_s) * (long)K + col_s;
  const u16* gA1 = gA0 + 64 * (long)K;
  const u16* gB0 = Bt + (bn + row_s) * (long)K + col_s;
  const u16* gB1 = gB0 + 64 * (long)K;
  u16* lA0 = &sA[wv * 512];            // wave-uniform base; lane*16B appended by HW
  u16* lA1 = &sA[2048 + wv * 512];
  u16* lB0 = &sB[wv * 512];
  u16* lB1 = &sB[2048 + wv * 512];

  for (int k0 = 0; k0 < K; k0 += 32) {
    async16(gA0 + k0, lA0);
    async16(gA1 + k0, lA1);
    async16(gB0 + k0, lB0);
    async16(gB1 + k0, lB1);
    __syncthreads();   // drains vmcnt: LDS tiles ready

    bf16x8 af[4], bf_[4];
#pragma unroll
    for (int mi = 0; mi < 4; mi++)
      af[mi] = *(const bf16x8*)&sA[(wm + mi * 16 + m16) * 32 + quad * 8];
#pragma unroll
    for (int ni = 0; ni < 4; ni++)
      bf_[ni] = *(const bf16x8*)&sB[(wn + ni * 16 + m16) * 32 + quad * 8];
#pragma unroll
    for (int mi = 0; mi < 4; mi++)
#pragma unroll
      for (int ni = 0; ni < 4; ni++)
        acc[mi][ni] = __builtin_amdgcn_mfma_f32_16x16x32_bf16(af[mi], bf_[ni], acc[mi][ni], 0, 0, 0);
    __syncthreads();   // protect tiles before next stage
  }

  float bv4[4];
#pragma unroll
  for (int ni = 0; ni < 4; ni++) bv4[ni] = bf2f(bias[bn + wn + ni * 16 + m16]);

#pragma unroll
  for (int mi = 0; mi < 4; mi++) {
#pragma unroll
    for (int ni = 0; ni < 4; ni++) {
      long col = bn + wn + ni * 16 + m16;
#pragma unroll
      for (int r = 0; r < 4; r++) {
        long row = bm + wm + mi * 16 + quad * 4 + r;
        float v = acc[mi][ni][r] + bv4[ni];
        if (act) v = fmaxf(v, 0.f);
        C[row * N + col] = f2bf(v);
      }
    }
  }
}

// ---------------- flash attention, S^T = K Q^T layout ----------------
// grid (S/64, B*H); 4 waves; wave w owns q rows [w*16, w*16+16); lane's q = lane&15.
// LDS 18.4 KB -> 8 blocks/CU. Softmax stats are per-lane scalars (2 shfl_xor per reduce).
__global__ __launch_bounds__(256) void attn_fwd(const u16* __restrict__ qkv,
                                                u16* __restrict__ attnO) {
  __shared__ alignas(16) u16 sQP[4608];  // Q [64][72]; later per-wave P[16][72] at wv*1152
  __shared__ alignas(16) u16 sK[4608];   // [key][dk] stride 72
  __shared__ alignas(16) u16 sVt[4608];  // [dk][key] stride 72
  const int tid = threadIdx.x;
  const int qt = blockIdx.x;
  const int bh = blockIdx.y;
  const int b = bh >> 4, h = bh & 15;
  const int wv = tid >> 6, lane = tid & 63;
  const int m16 = lane & 15, quad = lane >> 4;
  const int toct = tid & 7;
  const int r_0 = tid >> 3;              // staging row for i=0 (0..31)
  const int d_0 = (tid & 7) * 8;         // staging dk offset

  // stage Q [64 q][64 dk], pre-scaled by 1/sqrt(DK)=0.125 (exact, power of 2)
#pragma unroll
  for (int i = 0; i < 2; i++) {
    int r = i * 32 + r_0;
    const u16* g = qkv + ((long)(b * Sq + qt * 64 + r)) * 3072 + h * 64 + d_0;
    uint4 raw = *(const uint4*)g;
    const u16* pv = (const u16*)&raw;
    u16 t[8];
#pragma unroll
    for (int j = 0; j < 8; j++) t[j] = f2bf(bf2f(pv[j]) * 0.125f);
    *(uint4*)&sQP[r * 72 + d_0] = *(const uint4*)t;
  }
  __syncthreads();
  // Q^T B-fragments (B[k=quad*8+j][n=q=m16]); wave-private rows
  bf16x8 aq0 = *(const bf16x8*)&sQP[(wv * 16 + m16) * 72 + quad * 8];
  bf16x8 aq1 = *(const bf16x8*)&sQP[(wv * 16 + m16) * 72 + 32 + quad * 8];

  f32x4 oacc[4];
#pragma unroll
  for (int ni = 0; ni < 4; ni++) oacc[ni] = (f32x4){0.f, 0.f, 0.f, 0.f};
  float mrun = -1e30f, lrun = 0.f;

  // register prefetch of K/V for kt=0
  uint4 rk[2], rv[2];
#pragma unroll
  for (int i = 0; i < 2; i++) {
    long rowg = (long)(b * Sq + i * 32 + r_0) * 3072 + h * 64 + d_0;
    rk[i] = *(const uint4*)(qkv + rowg + 1024);
    rv[i] = *(const uint4*)(qkv + rowg + 2048);
  }

  for (int kt = 0; kt < 16; kt++) {
    __syncthreads();   // previous iteration's K/Vt reads done (kt=0: Q frags read)
#pragma unroll
    for (int i = 0; i < 2; i++) {
      int r = i * 32 + r_0;
      *(uint4*)&sK[r * 72 + d_0] = rk[i];
      const u16* pv = (const u16*)&rv[i];
#pragma unroll
      for (int j = 0; j < 8; j++) {       // V transpose, octet-rotated store order
        int jr = (j + toct) & 7;
        sVt[(d_0 + jr) * 72 + r] = pv[jr];
      }
    }
    __syncthreads();   // tiles published

    if (kt < 15) {     // prefetch next K/V (global latency overlaps compute)
#pragma unroll
      for (int i = 0; i < 2; i++) {
        long rowg = (long)(b * Sq + (kt + 1) * 64 + i * 32 + r_0) * 3072 + h * 64 + d_0;
        rk[i] = *(const uint4*)(qkv + rowg + 1024);
        rv[i] = *(const uint4*)(qkv + rowg + 2048);
      }
    }

    // S^T[key][q] = K Q^T : st[ni][r] = S^T[ni*16+quad*4+r][m16]
    f32x4 st[4];
#pragma unroll
    for (int ni = 0; ni < 4; ni++) st[ni] = (f32x4){0.f, 0.f, 0.f, 0.f};
#pragma unroll
    for (int ni = 0; ni < 4; ni++) {
      bf16x8 bk0 = *(const bf16x8*)&sK[(ni * 16 + m16) * 72 + quad * 8];
      bf16x8 bk1 = *(const bf16x8*)&sK[(ni * 16 + m16) * 72 + 32 + quad * 8];
      st[ni] = __builtin_amdgcn_mfma_f32_16x16x32_bf16(bk0, aq0, st[ni], 0, 0, 0);
      st[ni] = __builtin_amdgcn_mfma_f32_16x16x32_bf16(bk1, aq1, st[ni], 0, 0, 0);
    }

    // online softmax: all 16 st values share q=m16 -> scalar stats per lane
    float pmax = st[0][0];
#pragma unroll
    for (int ni = 0; ni < 4; ni++)
#pragma unroll
      for (int r = 0; r < 4; r++) pmax = fmaxf(pmax, st[ni][r]);
    pmax = fmaxf(pmax, __shfl_xor(pmax, 16));
    pmax = fmaxf(pmax, __shfl_xor(pmax, 32));
    float mnew = fmaxf(mrun, pmax);
    float alpha = __expf(mrun - mnew);
    float ps[4][4];
    float rs = 0.f;
#pragma unroll
    for (int ni = 0; ni < 4; ni++)
#pragma unroll
      for (int r = 0; r < 4; r++) {
        float p = __expf(st[ni][r] - mnew);
        ps[ni][r] = p; rs += p;
      }
    rs += __shfl_xor(rs, 16);
    rs += __shfl_xor(rs, 32);
    mrun = mnew;
    lrun = lrun * alpha + rs;
#pragma unroll
    for (int ni = 0; ni < 4; ni++)
#pragma unroll
      for (int r = 0; r < 4; r++) oacc[ni][r] *= alpha;

    // P^T(C-layout) -> LDS as P[q][key] rows (stride 72): 4x ds_write_b64, wave-private
    u16* sPw = &sQP[wv * 1152];
#pragma unroll
    for (int ni = 0; ni < 4; ni++) {
      u16 t[4];
#pragma unroll
      for (int r = 0; r < 4; r++) t[r] = f2bf(ps[ni][r]);
      *(uint2*)&sPw[m16 * 72 + ni * 16 + quad * 4] = *(const uint2*)t;
    }
    // P^T B-frags: B[k=c*32+quad*8+j][n=q=m16] = P[m16][c*32+quad*8+j]
    bf16x8 pb0 = *(const bf16x8*)&sPw[m16 * 72 + quad * 8];
    bf16x8 pb1 = *(const bf16x8*)&sPw[m16 * 72 + 32 + quad * 8];

    // O^T += V^T P^T : A = V^T[dk][key] from sVt
#pragma unroll
    for (int ni = 0; ni < 4; ni++) {
      bf16x8 av0 = *(const bf16x8*)&sVt[(ni * 16 + m16) * 72 + quad * 8];
      bf16x8 av1 = *(const bf16x8*)&sVt[(ni * 16 + m16) * 72 + 32 + quad * 8];
      oacc[ni] = __builtin_amdgcn_mfma_f32_16x16x32_bf16(av0, pb0, oacc[ni], 0, 0, 0);
      oacc[ni] = __builtin_amdgcn_mfma_f32_16x16x32_bf16(av1, pb1, oacc[ni], 0, 0, 0);
    }
  }

  // O^T C-layout: lane holds O[q=m16][dk=ni*16+quad*4+r] -> 4 contiguous dk per uint2
  float rl = 1.f / lrun;
  long row = (long)(b * Sq + qt * 64 + wv * 16 + m16);
#pragma unroll
  for (int ni = 0; ni < 4; ni++) {
    u16 t[4];
#pragma unroll
    for (int r = 0; r < 4; r++) t[r] = f2bf(oacc[ni][r] * rl);
    *(uint2*)&attnO[row * 1024 + h * 64 + ni * 16 + quad * 4] = *(const uint2*)t;
  }
}

// ---------------- add + LayerNorm (bf16 out, internal) ----------------
__global__ __launch_bounds__(256) void add_ln(const u16* __restrict__ X,
                                              const u16* __restrict__ Y,
                                              const u16* __restrict__ g,
                                              const u16* __restrict__ be,
                                              u16* __restrict__ out) {
  const int row = blockIdx.x;
  const int t = threadIdx.x;
  const long base = (long)row * Dq;
  float v[4]; float s = 0.f, ss = 0.f;
#pragma unroll
  for (int i = 0; i < 4; i++) {
    int idx = i * 256 + t;
    float x = bf2f(X[base + idx]) + bf2f(Y[base + idx]);
    v[i] = x; s += x; ss += x * x;
  }
#pragma unroll
  for (int off = 32; off > 0; off >>= 1) { s += __shfl_down(s, off); ss += __shfl_down(ss, off); }
  __shared__ float red[8];
  int wv = t >> 6, ln = t & 63;
  if (ln == 0) { red[wv] = s; red[4 + wv] = ss; }
  __syncthreads();
  s = red[0] + red[1] + red[2] + red[3];
  ss = red[4] + red[5] + red[6] + red[7];
  float mean = s * (1.f / Dq);
  float var = ss * (1.f / Dq) - mean * mean;
  float rstd = rsqrtf(var + 1e-5f);
#pragma unroll
  for (int i = 0; i < 4; i++) {
    int idx = i * 256 + t;
    float o = (v[i] - mean) * rstd * bf2f(g[idx]) + bf2f(be[idx]);
    out[base + idx] = f2bf(o);
  }
}

// ---------------- final add + LayerNorm, dual-dtype store ----------------
__global__ __launch_bounds__(256) void add_ln_out(const u16* __restrict__ X,
                                                  const u16* __restrict__ Y,
                                                  const u16* __restrict__ g,
                                                  const u16* __restrict__ be,
                                                  void* __restrict__ out,
                                                  const u32* __restrict__ outflag) {
  const u32 fp32 = *outflag;
  const int row = blockIdx.x;
  const int t = threadIdx.x;
  const long base = (long)row * Dq;
  float v[4]; float s = 0.f, ss = 0.f;
#pragma unroll
  for (int i = 0; i < 4; i++) {
    int idx = i * 256 + t;
    float x = bf2f(X[base + idx]) + bf2f(Y[base + idx]);
    v[i] = x; s += x; ss += x * x;
  }
#pragma unroll
  for (int off = 32; off > 0; off >>= 1) { s += __shfl_down(s, off); ss += __shfl_down(ss, off); }
  __shared__ float red[8];
  int wv = t >> 6, ln = t & 63;
  if (ln == 0) { red[wv] = s; red[4 + wv] = ss; }
  __syncthreads();
  s = red[0] + red[1] + red[2] + red[3];
  ss = red[4] + red[5] + red[6] + red[7];
  float mean = s * (1.f / Dq);
  float var = ss * (1.f / Dq) - mean * mean;
  float rstd = rsqrtf(var + 1e-5f);
#pragma unroll
  for (int i = 0; i < 4; i++) {
    int idx = i * 256 + t;
    float o = (v[i] - mean) * rstd * bf2f(g[idx]) + bf2f(be[idx]);
    if (fp32) ((float*)out)[base + idx] = o;
    else ((u16*)out)[base + idx] = f2bf(o);
  }
}

extern "C" void kernel_launch(void* const* d_in, const int* in_sizes, int n_in,
                              void* d_out, int out_size, void* d_ws, size_t ws_size,
                              hipStream_t stream) {
  char* ws = (char*)d_ws;
  size_t off = 0;
  auto alloc = [&](size_t bytes) {
    void* p = ws + off;
    off += (bytes + 255) & ~(size_t)255;
    return p;
  };
  u32* flags  = (u32*)alloc(32 * 4);
  u16* Wqkv_t = (u16*)alloc((size_t)3072 * 1024 * 2);   // 6 MB
  u16* Wo_t   = (u16*)alloc((size_t)1024 * 1024 * 2);   // 2 MB
  u16* W1_t   = (u16*)alloc((size_t)4096 * 1024 * 2);   // 8 MB
  u16* W2_t   = (u16*)alloc((size_t)1024 * 4096 * 2);   // 8 MB
  u16* svec   = (u16*)alloc((size_t)13312 * 2);         // all small vectors
  u16* src_bf = (u16*)alloc((size_t)TOK * 1024 * 2);    // 16 MB
  u16* regA   = (u16*)alloc((size_t)TOK * 4096 * 2);    // 64 MB
  size_t need_chunk2 = off;                              // h1(32MB) fits inside regA
  size_t need_full   = off + (size_t)TOK * 4096 * 2 / 2; // +32MB so h1(64MB) spans past regA

  u16* outw = (u16*)d_out;
  // pick FF chunking by available workspace
  int CH;  // rows per FF chunk
  if (ws_size >= need_full) { CH = 8192; (void)alloc((size_t)32 << 20); }
  else if (ws_size >= need_chunk2) CH = 4096;
  else if (ws_size >= need_chunk2 - ((size_t)16 << 20)) CH = 2048;  // h1c 16MB
  else {
    diag_ws_too_small<<<1, 1, 0, stream>>>(outw, 8000.0f + (float)(ws_size >> 20));
    return;
  }

  u16* qkv   = regA;                          // [0,48) MB
  u16* attnb = regA + (size_t)TOK * 3072;     // [48,64) MB
  u16* proj  = regA;                          // [0,16)  after qkv dead
  u16* x     = regA + (size_t)TOK * 1024;     // [16,32)
  u16* h1    = regA + (size_t)TOK * 2048;     // [32,..) CH*4096*2 bytes
  u16* f2    = src_bf;                        // src_bf dead after x computed

  // small-vector offsets inside svec
  u16* bqkv = svec + 0;      // 3072
  u16* bo_c = svec + 3072;   // 1024
  u16* g1_c = svec + 4096;
  u16* be1_c = svec + 5120;
  u16* b1_c = svec + 6144;   // 4096
  u16* b2_c = svec + 10240;
  u16* g2_c = svec + 11264;
  u16* be2_c = svec + 12288;

  // ---- dtype detection: one launch ----
  InTab itab;
  for (int i = 0; i < 17; i++) { itab.p[i] = d_in[i]; itab.n[i] = in_sizes[i]; }
  detect_all<<<dim3(17), 256, 0, stream>>>(itab, flags);

  // ---- weight packs (coalesced tiled transpose) ----
  transpose_pack<<<dim3(16, 1, 16), dim3(64, 4), 0, stream>>>(d_in[1], Wqkv_t,            65536, 65536, 1024, 64, &flags[1]);
  transpose_pack<<<dim3(16, 1, 16), dim3(64, 4), 0, stream>>>(d_in[3], Wqkv_t + 1048576,  65536, 65536, 1024, 64, &flags[3]);
  transpose_pack<<<dim3(16, 1, 16), dim3(64, 4), 0, stream>>>(d_in[5], Wqkv_t + 2097152,  65536, 65536, 1024, 64, &flags[5]);
  transpose_pack<<<dim3(16, 16, 1), dim3(64, 4), 0, stream>>>(d_in[7],  Wo_t, 0, 0, 1024, 1024, &flags[7]);
  transpose_pack<<<dim3(16, 64, 1), dim3(64, 4), 0, stream>>>(d_in[11], W1_t, 0, 0, 1024, 4096, &flags[11]);
  transpose_pack<<<dim3(64, 16, 1), dim3(64, 4), 0, stream>>>(d_in[13], W2_t, 0, 0, 4096, 1024, &flags[13]);

  // ---- small vectors: one launch ----
  CvtTab ct;
  const int srcs[10]   = {2, 4, 6, 8, 9, 10, 12, 14, 15, 16};
  const int offs[10]   = {0, 1024, 2048, 3072, 4096, 5120, 6144, 10240, 11264, 12288};
  const int lens[10]   = {1024, 1024, 1024, 1024, 1024, 1024, 4096, 1024, 1024, 1024};
  for (int e = 0; e < 10; e++) { ct.p[e] = d_in[srcs[e]]; ct.flagidx[e] = srcs[e]; ct.dstoff[e] = offs[e]; ct.n[e] = lens[e]; }
  cvt_small<<<dim3(10), 256, 0, stream>>>(ct, svec, flags);

  // ---- src -> bf16 ----
  cvt_src<<<dim3(TOK * 1024 / (256 * 8)), 256, 0, stream>>>(d_in[0], src_bf, &flags[0]);

  // qkv = src @ Wqkv + b           [8192,3072]
  gemm_bt<<<dim3(64, 24), 256, 0, stream>>>(src_bf, Wqkv_t, bqkv, qkv, TOK, 3072, 1024, 0);
  // attention                       [8192,1024]
  attn_fwd<<<dim3(16, 128), 256, 0, stream>>>(qkv, attnb);
  // proj = attn @ Wo + bo
  gemm_bt<<<dim3(64, 8), 256, 0, stream>>>(attnb, Wo_t, bo_c, proj, TOK, 1024, 1024, 0);
  // x = LN(src + proj)
  add_ln<<<dim3(TOK), 256, 0, stream>>>(src_bf, proj, g1_c, be1_c, x);
  // FF: h1 = relu(x@W1+b1); f2 = h1@W2+b2, chunked by CH rows
  for (int c = 0; c < TOK / CH; c++) {
    const u16* xc = x + (size_t)c * CH * 1024;
    u16* f2c = f2 + (size_t)c * CH * 1024;
    gemm_bt<<<dim3(CH / 128, 32), 256, 0, stream>>>(xc, W1_t, b1_c, h1, CH, 4096, 1024, 1);
    gemm_bt<<<dim3(CH / 128, 8), 256, 0, stream>>>(h1, W2_t, b2_c, f2c, CH, 1024, 4096, 0);
  }
  // out = LN(x + f2), stored in src's container dtype
  add_ln_out<<<dim3(TOK), 256, 0, stream>>>(x, f2, g2_c, be2_c, d_out, &flags[0]);
  diag_mixed<<<1, 1, 0, stream>>>(flags, d_out);
}

// Round 7
// 696.751 us; speedup vs baseline: 1.0938x; 1.0938x over previous
//
#include <hip/hip_runtime.h>

// B=8 S=1024 D=1024 H=16 DK=64 F=4096 -- fp32 containers (bf16-valued), detected per-tensor
#define Bq 8
#define Sq 1024
#define Dq 1024
#define Hq 16
#define DKq 64
#define Fq 4096
#define TOK (Bq*Sq)   // 8192

typedef unsigned short u16;
typedef unsigned int u32;
typedef __bf16 bf16x8 __attribute__((ext_vector_type(8)));
typedef float  f32x4  __attribute__((ext_vector_type(4)));

__device__ __forceinline__ float bf2f(u16 u) {
  u32 x = ((u32)u) << 16;
  float f; __builtin_memcpy(&f, &x, 4); return f;
}
__device__ __forceinline__ u16 f2bf(float f) {
  u32 u; __builtin_memcpy(&u, &f, 4);
  u += 0x7fffu + ((u >> 16) & 1u);
  return (u16)(u >> 16);
}
// async global->LDS, 16B/lane; LDS dest = wave-uniform base + lane*16
__device__ __forceinline__ void async16(const u16* g, u16* l) {
  __builtin_amdgcn_global_load_lds(
      (__attribute__((address_space(1))) void*)(g),
      (__attribute__((address_space(3))) void*)(l), 16, 0, 0);
}
__device__ __forceinline__ u16 load_in(const void* p, long idx, u32 fp32) {
  return fp32 ? f2bf(((const float*)p)[idx]) : ((const u16*)p)[idx];
}

// ---------------- dtype detection: one launch, 17 blocks ----------------
struct InTab { const void* p[17]; int n[17]; };

__global__ void detect_all(InTab tab, u32* flags) {
  __shared__ int sh[3][256];
  int bi = blockIdx.x;
  const u16* buf = (const u16*)tab.p[bi];
  long n = tab.n[bi];
  long m = n < 65536 ? n : 65536;
  int t = threadIdx.x;
  int nanpat = 0, evz = 0, oddnz = 0;
  for (long i = t; i < m; i += 256) {
    u16 v = buf[i];
    if ((v & 0x7F80u) == 0x7F80u) nanpat++;
    if ((i & 1) == 0) { if (v == 0) evz++; }
    else { if (v != 0) oddnz++; }
  }
  sh[0][t] = nanpat; sh[1][t] = evz; sh[2][t] = oddnz;
  __syncthreads();
  for (int s = 128; s > 0; s >>= 1) {
    if (t < s) { sh[0][t] += sh[0][t+s]; sh[1][t] += sh[1][t+s]; sh[2][t] += sh[2][t+s]; }
    __syncthreads();
  }
  if (t == 0) {
    long half = m / 2;
    bool fp32 = (sh[0][0] > 8) ||
                (sh[1][0] > (half * 9) / 10 && sh[2][0] > (half * 9) / 10);
    flags[bi] = fp32 ? 1u : 0u;
  }
}

__global__ void diag_ws_too_small(u16* out, float code) { out[0] = f2bf(code); }

__global__ void diag_mixed(const u32* flags, void* out) {
  u32 a = flags[0];
  if (flags[1] != a || flags[7] != a || flags[11] != a || flags[13] != a) {
    if (a) ((float*)out)[0] = 3000.0f;
    else ((u16*)out)[0] = f2bf(3000.0f);
  }
}

// ---------------- LDS-tiled transpose pack: in[Z][R][C] -> out u16 [Z][C][R] ----
// grid (R/64, C/64, Z), block (64,4)
__global__ __launch_bounds__(256) void transpose_pack(const void* __restrict__ in,
                                                      u16* __restrict__ out,
                                                      long zsi, long zso, int R, int C,
                                                      const u32* __restrict__ flag) {
  u32 f = *flag;
  __shared__ u16 tile[64][65];
  int tx = threadIdx.x, ty = threadIdx.y;
  int r0 = blockIdx.x * 64, c0 = blockIdx.y * 64;
  long zin = (long)blockIdx.z * zsi, zout = (long)blockIdx.z * zso;
#pragma unroll
  for (int it = 0; it < 16; it++) {
    int row = it * 4 + ty;
    tile[row][tx] = load_in(in, zin + (long)(r0 + row) * C + (c0 + tx), f);
  }
  __syncthreads();
#pragma unroll
  for (int it = 0; it < 16; it++) {
    int cc = it * 4 + ty;
    out[zout + (long)(c0 + cc) * R + r0 + tx] = tile[tx][cc];
  }
}

// ---------------- merged small-vector cvt ----------------
struct CvtTab { const void* p[10]; int flagidx[10]; int dstoff[10]; int n[10]; };
__global__ void cvt_small(CvtTab tab, u16* __restrict__ dst, const u32* __restrict__ flags) {
  int e = blockIdx.x;
  u32 f = flags[tab.flagidx[e]];
  const void* p = tab.p[e];
  int n = tab.n[e], o = tab.dstoff[e];
  for (int i = threadIdx.x; i < n; i += 256) dst[o + i] = load_in(p, i, f);
}

// ---------------- vectorized src cvt (8 elems/thread) ----------------
__global__ __launch_bounds__(256) void cvt_src(const void* __restrict__ in,
                                               u16* __restrict__ out,
                                               const u32* __restrict__ flag) {
  u32 f = *flag;
  long i8 = ((long)blockIdx.x * 256 + threadIdx.x) * 8;
  if (f) {
    const float4* f4 = (const float4*)((const float*)in + i8);
    float4 a = f4[0], b = f4[1];
    u16 v[8] = {f2bf(a.x), f2bf(a.y), f2bf(a.z), f2bf(a.w),
                f2bf(b.x), f2bf(b.y), f2bf(b.z), f2bf(b.w)};
    *(uint4*)(out + i8) = *(const uint4*)v;
  } else {
    *(uint4*)(out + i8) = *(const uint4*)((const u16*)in + i8);
  }
}

// ---------------- GEMM: C[M,N] = A[M,K] @ Bt[N,K]^T + bias, optional ReLU --------
// 128x128 tile, BK=32, 4 waves each 64x64, 16x16x32 bf16 MFMA, global_load_lds staging
__global__ __launch_bounds__(256) void gemm_bt(const u16* __restrict__ A,
                                               const u16* __restrict__ Bt,
                                               const u16* __restrict__ bias,
                                               u16* __restrict__ C,
                                               int M, int N, int K, int act) {
  __shared__ alignas(16) u16 sA[128 * 32];
  __shared__ alignas(16) u16 sB[128 * 32];
  const int tid = threadIdx.x;
  const int wv = tid >> 6, lane = tid & 63;
  const int m16 = lane & 15, quad = lane >> 4;
  const long bm = (long)blockIdx.x * 128;
  const long bn = (long)blockIdx.y * 128;
  const int wm = (wv >> 1) * 64, wn = (wv & 1) * 64;

  f32x4 acc[4][4];
#pragma unroll
  for (int i = 0; i < 4; i++)
#pragma unroll
    for (int j = 0; j < 4; j++) acc[i][j] = (f32x4){0.f, 0.f, 0.f, 0.f};

  // staging: thread t covers 8 contiguous bf16; tile image row-major [128][32]
  const int row_s = tid >> 2;          // 0..63
  const int col_s = (tid & 3) * 8;
  const u16* gA0 = A + (bm + row_s) * (long)K + col_s;
  const u16* gA1 = gA0 + 64 * (long)K;
  const u16* gB0 = Bt + (bn + row_s) * (long)K + col_s;
  const u16* gB1 = gB0 + 64 * (long)K;
  u16* lA0 = &sA[wv * 512];            // wave-uniform base; lane*16B appended by HW
  u16* lA1 = &sA[2048 + wv * 512];
  u16* lB0 = &sB[wv * 512];
  u16* lB1 = &sB[2048 + wv * 512];

  for (int k0 = 0; k0 < K; k0 += 32) {
    async16(gA0 + k0, lA0);
    async16(gA1 + k0, lA1);
    async16(gB0 + k0, lB0);
    async16(gB1 + k0, lB1);
    __syncthreads();   // drains vmcnt: LDS tiles ready

    bf16x8 af[4], bf_[4];
#pragma unroll
    for (int mi = 0; mi < 4; mi++)
      af[mi] = *(const bf16x8*)&sA[(wm + mi * 16 + m16) * 32 + quad * 8];
#pragma unroll
    for (int ni = 0; ni < 4; ni++)
      bf_[ni] = *(const bf16x8*)&sB[(wn + ni * 16 + m16) * 32 + quad * 8];
#pragma unroll
    for (int mi = 0; mi < 4; mi++)
#pragma unroll
      for (int ni = 0; ni < 4; ni++)
        acc[mi][ni] = __builtin_amdgcn_mfma_f32_16x16x32_bf16(af[mi], bf_[ni], acc[mi][ni], 0, 0, 0);
    __syncthreads();   // protect tiles before next stage
  }

  float bv4[4];
#pragma unroll
  for (int ni = 0; ni < 4; ni++) bv4[ni] = bf2f(bias[bn + wn + ni * 16 + m16]);

#pragma unroll
  for (int mi = 0; mi < 4; mi++) {
#pragma unroll
    for (int ni = 0; ni < 4; ni++) {
      long col = bn + wn + ni * 16 + m16;
#pragma unroll
      for (int r = 0; r < 4; r++) {
        long row = bm + wm + mi * 16 + quad * 4 + r;
        float v = acc[mi][ni][r] + bv4[ni];
        if (act) v = fmaxf(v, 0.f);
        C[row * N + col] = f2bf(v);
      }
    }
  }
}

// ---------------- flash attention, S^T = K Q^T layout ----------------
// grid (S/64, B*H); 4 waves; wave w owns q rows [w*16, w*16+16); lane's q = lane&15.
// LDS 18.4 KB. __launch_bounds__(256,4): 4 waves/EU -> VGPR cap 128, NO spill of the
// K/V prefetch registers (round-6 regression: VGPR=64 cap spilled 340 MB to scratch).
__global__ __launch_bounds__(256, 4) void attn_fwd(const u16* __restrict__ qkv,
                                                   u16* __restrict__ attnO) {
  __shared__ alignas(16) u16 sQP[4608];  // Q [64][72]; later per-wave P[16][72] at wv*1152
  __shared__ alignas(16) u16 sK[4608];   // [key][dk] stride 72
  __shared__ alignas(16) u16 sVt[4608];  // [dk][key] stride 72
  const int tid = threadIdx.x;
  const int qt = blockIdx.x;
  const int bh = blockIdx.y;
  const int b = bh >> 4, h = bh & 15;
  const int wv = tid >> 6, lane = tid & 63;
  const int m16 = lane & 15, quad = lane >> 4;
  const int toct = tid & 7;
  const int r_0 = tid >> 3;              // staging row for i=0 (0..31)
  const int d_0 = (tid & 7) * 8;         // staging dk offset

  // stage Q [64 q][64 dk], pre-scaled by 1/sqrt(DK)=0.125 (exact, power of 2)
#pragma unroll
  for (int i = 0; i < 2; i++) {
    int r = i * 32 + r_0;
    const u16* g = qkv + ((long)(b * Sq + qt * 64 + r)) * 3072 + h * 64 + d_0;
    uint4 raw = *(const uint4*)g;
    const u16* pv = (const u16*)&raw;
    u16 t[8];
#pragma unroll
    for (int j = 0; j < 8; j++) t[j] = f2bf(bf2f(pv[j]) * 0.125f);
    *(uint4*)&sQP[r * 72 + d_0] = *(const uint4*)t;
  }
  __syncthreads();
  // Q^T B-fragments (B[k=quad*8+j][n=q=m16]); wave-private rows
  bf16x8 aq0 = *(const bf16x8*)&sQP[(wv * 16 + m16) * 72 + quad * 8];
  bf16x8 aq1 = *(const bf16x8*)&sQP[(wv * 16 + m16) * 72 + 32 + quad * 8];

  f32x4 oacc[4];
#pragma unroll
  for (int ni = 0; ni < 4; ni++) oacc[ni] = (f32x4){0.f, 0.f, 0.f, 0.f};
  float mrun = -1e30f, lrun = 0.f;

  // incrementing K/V base pointers (staging rows r_0 and r_0+32)
  const u16* gK0 = qkv + (long)(b * Sq + r_0) * 3072 + h * 64 + d_0 + 1024;
  const u16* gK1 = gK0 + 32 * 3072;
  const long step = 64 * 3072;

  // register prefetch of K/V for kt=0
  uint4 rk0 = *(const uint4*)gK0;
  uint4 rk1 = *(const uint4*)gK1;
  uint4 rv0 = *(const uint4*)(gK0 + 1024);
  uint4 rv1 = *(const uint4*)(gK1 + 1024);

  for (int kt = 0; kt < 16; kt++) {
    __syncthreads();   // previous iteration's K/Vt reads done (kt=0: Q frags read)
    *(uint4*)&sK[r_0 * 72 + d_0] = rk0;
    *(uint4*)&sK[(r_0 + 32) * 72 + d_0] = rk1;
    {
      const u16* pv0 = (const u16*)&rv0;
      const u16* pv1 = (const u16*)&rv1;
#pragma unroll
      for (int j = 0; j < 8; j++) {       // V transpose, octet-rotated store order
        int jr = (j + toct) & 7;
        sVt[(d_0 + jr) * 72 + r_0] = pv0[jr];
        sVt[(d_0 + jr) * 72 + r_0 + 32] = pv1[jr];
      }
    }
    __syncthreads();   // tiles published

    if (kt < 15) {     // prefetch next K/V (global latency overlaps compute)
      const u16* nK0 = gK0 + (long)(kt + 1) * step;
      const u16* nK1 = gK1 + (long)(kt + 1) * step;
      rk0 = *(const uint4*)nK0;
      rk1 = *(const uint4*)nK1;
      rv0 = *(const uint4*)(nK0 + 1024);
      rv1 = *(const uint4*)(nK1 + 1024);
    }

    // S^T[key][q] = K Q^T : st[ni][r] = S^T[ni*16+quad*4+r][m16]
    f32x4 st[4];
#pragma unroll
    for (int ni = 0; ni < 4; ni++) st[ni] = (f32x4){0.f, 0.f, 0.f, 0.f};
#pragma unroll
    for (int ni = 0; ni < 4; ni++) {
      bf16x8 bk0 = *(const bf16x8*)&sK[(ni * 16 + m16) * 72 + quad * 8];
      bf16x8 bk1 = *(const bf16x8*)&sK[(ni * 16 + m16) * 72 + 32 + quad * 8];
      st[ni] = __builtin_amdgcn_mfma_f32_16x16x32_bf16(bk0, aq0, st[ni], 0, 0, 0);
      st[ni] = __builtin_amdgcn_mfma_f32_16x16x32_bf16(bk1, aq1, st[ni], 0, 0, 0);
    }

    // online softmax: all 16 st values share q=m16 -> scalar stats per lane
    float pmax = st[0][0];
#pragma unroll
    for (int ni = 0; ni < 4; ni++)
#pragma unroll
      for (int r = 0; r < 4; r++) pmax = fmaxf(pmax, st[ni][r]);
    pmax = fmaxf(pmax, __shfl_xor(pmax, 16));
    pmax = fmaxf(pmax, __shfl_xor(pmax, 32));
    float mnew = fmaxf(mrun, pmax);
    float alpha = __expf(mrun - mnew);
    float ps[4][4];
    float rs = 0.f;
#pragma unroll
    for (int ni = 0; ni < 4; ni++)
#pragma unroll
      for (int r = 0; r < 4; r++) {
        float p = __expf(st[ni][r] - mnew);
        ps[ni][r] = p; rs += p;
      }
    rs += __shfl_xor(rs, 16);
    rs += __shfl_xor(rs, 32);
    mrun = mnew;
    lrun = lrun * alpha + rs;
#pragma unroll
    for (int ni = 0; ni < 4; ni++)
#pragma unroll
      for (int r = 0; r < 4; r++) oacc[ni][r] *= alpha;

    // P^T(C-layout) -> LDS as P[q][key] rows (stride 72): 4x ds_write_b64, wave-private
    u16* sPw = &sQP[wv * 1152];
#pragma unroll
    for (int ni = 0; ni < 4; ni++) {
      u16 t[4];
#pragma unroll
      for (int r = 0; r < 4; r++) t[r] = f2bf(ps[ni][r]);
      *(uint2*)&sPw[m16 * 72 + ni * 16 + quad * 4] = *(const uint2*)t;
    }
    // P^T B-frags: B[k=c*32+quad*8+j][n=q=m16] = P[m16][c*32+quad*8+j]
    bf16x8 pb0 = *(const bf16x8*)&sPw[m16 * 72 + quad * 8];
    bf16x8 pb1 = *(const bf16x8*)&sPw[m16 * 72 + 32 + quad * 8];

    // O^T += V^T P^T : A = V^T[dk][key] from sVt
#pragma unroll
    for (int ni = 0; ni < 4; ni++) {
      bf16x8 av0 = *(const bf16x8*)&sVt[(ni * 16 + m16) * 72 + quad * 8];
      bf16x8 av1 = *(const bf16x8*)&sVt[(ni * 16 + m16) * 72 + 32 + quad * 8];
      oacc[ni] = __builtin_amdgcn_mfma_f32_16x16x32_bf16(av0, pb0, oacc[ni], 0, 0, 0);
      oacc[ni] = __builtin_amdgcn_mfma_f32_16x16x32_bf16(av1, pb1, oacc[ni], 0, 0, 0);
    }
  }

  // O^T C-layout: lane holds O[q=m16][dk=ni*16+quad*4+r] -> 4 contiguous dk per uint2
  float rl = 1.f / lrun;
  long row = (long)(b * Sq + qt * 64 + wv * 16 + m16);
#pragma unroll
  for (int ni = 0; ni < 4; ni++) {
    u16 t[4];
#pragma unroll
    for (int r = 0; r < 4; r++) t[r] = f2bf(oacc[ni][r] * rl);
    *(uint2*)&attnO[row * 1024 + h * 64 + ni * 16 + quad * 4] = *(const uint2*)t;
  }
}

// ---------------- add + LayerNorm (bf16 out, internal) ----------------
__global__ __launch_bounds__(256) void add_ln(const u16* __restrict__ X,
                                              const u16* __restrict__ Y,
                                              const u16* __restrict__ g,
                                              const u16* __restrict__ be,
                                              u16* __restrict__ out) {
  const int row = blockIdx.x;
  const int t = threadIdx.x;
  const long base = (long)row * Dq;
  float v[4]; float s = 0.f, ss = 0.f;
#pragma unroll
  for (int i = 0; i < 4; i++) {
    int idx = i * 256 + t;
    float x = bf2f(X[base + idx]) + bf2f(Y[base + idx]);
    v[i] = x; s += x; ss += x * x;
  }
#pragma unroll
  for (int off = 32; off > 0; off >>= 1) { s += __shfl_down(s, off); ss += __shfl_down(ss, off); }
  __shared__ float red[8];
  int wv = t >> 6, ln = t & 63;
  if (ln == 0) { red[wv] = s; red[4 + wv] = ss; }
  __syncthreads();
  s = red[0] + red[1] + red[2] + red[3];
  ss = red[4] + red[5] + red[6] + red[7];
  float mean = s * (1.f / Dq);
  float var = ss * (1.f / Dq) - mean * mean;
  float rstd = rsqrtf(var + 1e-5f);
#pragma unroll
  for (int i = 0; i < 4; i++) {
    int idx = i * 256 + t;
    float o = (v[i] - mean) * rstd * bf2f(g[idx]) + bf2f(be[idx]);
    out[base + idx] = f2bf(o);
  }
}

// ---------------- final add + LayerNorm, dual-dtype store ----------------
__global__ __launch_bounds__(256) void add_ln_out(const u16* __restrict__ X,
                                                  const u16* __restrict__ Y,
                                                  const u16* __restrict__ g,
                                                  const u16* __restrict__ be,
                                                  void* __restrict__ out,
                                                  const u32* __restrict__ outflag) {
  const u32 fp32 = *outflag;
  const int row = blockIdx.x;
  const int t = threadIdx.x;
  const long base = (long)row * Dq;
  float v[4]; float s = 0.f, ss = 0.f;
#pragma unroll
  for (int i = 0; i < 4; i++) {
    int idx = i * 256 + t;
    float x = bf2f(X[base + idx]) + bf2f(Y[base + idx]);
    v[i] = x; s += x; ss += x * x;
  }
#pragma unroll
  for (int off = 32; off > 0; off >>= 1) { s += __shfl_down(s, off); ss += __shfl_down(ss, off); }
  __shared__ float red[8];
  int wv = t >> 6, ln = t & 63;
  if (ln == 0) { red[wv] = s; red[4 + wv] = ss; }
  __syncthreads();
  s = red[0] + red[1] + red[2] + red[3];
  ss = red[4] + red[5] + red[6] + red[7];
  float mean = s * (1.f / Dq);
  float var = ss * (1.f / Dq) - mean * mean;
  float rstd = rsqrtf(var + 1e-5f);
#pragma unroll
  for (int i = 0; i < 4; i++) {
    int idx = i * 256 + t;
    float o = (v[i] - mean) * rstd * bf2f(g[idx]) + bf2f(be[idx]);
    if (fp32) ((float*)out)[base + idx] = o;
    else ((u16*)out)[base + idx] = f2bf(o);
  }
}

extern "C" void kernel_launch(void* const* d_in, const int* in_sizes, int n_in,
                              void* d_out, int out_size, void* d_ws, size_t ws_size,
                              hipStream_t stream) {
  char* ws = (char*)d_ws;
  size_t off = 0;
  auto alloc = [&](size_t bytes) {
    void* p = ws + off;
    off += (bytes + 255) & ~(size_t)255;
    return p;
  };
  u32* flags  = (u32*)alloc(32 * 4);
  u16* Wqkv_t = (u16*)alloc((size_t)3072 * 1024 * 2);   // 6 MB
  u16* Wo_t   = (u16*)alloc((size_t)1024 * 1024 * 2);   // 2 MB
  u16* W1_t   = (u16*)alloc((size_t)4096 * 1024 * 2);   // 8 MB
  u16* W2_t   = (u16*)alloc((size_t)1024 * 4096 * 2);   // 8 MB
  u16* svec   = (u16*)alloc((size_t)13312 * 2);         // all small vectors
  u16* src_bf = (u16*)alloc((size_t)TOK * 1024 * 2);    // 16 MB
  u16* regA   = (u16*)alloc((size_t)TOK * 4096 * 2);    // 64 MB
  size_t need_chunk2 = off;                              // h1(32MB) fits inside regA
  size_t need_full   = off + (size_t)TOK * 4096 * 2 / 2; // +32MB so h1(64MB) spans past regA

  u16* outw = (u16*)d_out;
  // pick FF chunking by available workspace
  int CH;  // rows per FF chunk
  if (ws_size >= need_full) { CH = 8192; (void)alloc((size_t)32 << 20); }
  else if (ws_size >= need_chunk2) CH = 4096;
  else if (ws_size >= need_chunk2 - ((size_t)16 << 20)) CH = 2048;  // h1c 16MB
  else {
    diag_ws_too_small<<<1, 1, 0, stream>>>(outw, 8000.0f + (float)(ws_size >> 20));
    return;
  }

  u16* qkv   = regA;                          // [0,48) MB
  u16* attnb = regA + (size_t)TOK * 3072;     // [48,64) MB
  u16* proj  = regA;                          // [0,16)  after qkv dead
  u16* x     = regA + (size_t)TOK * 1024;     // [16,32)
  u16* h1    = regA + (size_t)TOK * 2048;     // [32,..) CH*4096*2 bytes
  u16* f2    = src_bf;                        // src_bf dead after x computed

  // small-vector offsets inside svec
  u16* bqkv = svec + 0;      // 3072
  u16* bo_c = svec + 3072;   // 1024
  u16* g1_c = svec + 4096;
  u16* be1_c = svec + 5120;
  u16* b1_c = svec + 6144;   // 4096
  u16* b2_c = svec + 10240;
  u16* g2_c = svec + 11264;
  u16* be2_c = svec + 12288;

  // ---- dtype detection: one launch ----
  InTab itab;
  for (int i = 0; i < 17; i++) { itab.p[i] = d_in[i]; itab.n[i] = in_sizes[i]; }
  detect_all<<<dim3(17), 256, 0, stream>>>(itab, flags);

  // ---- weight packs (coalesced tiled transpose) ----
  transpose_pack<<<dim3(16, 1, 16), dim3(64, 4), 0, stream>>>(d_in[1], Wqkv_t,            65536, 65536, 1024, 64, &flags[1]);
  transpose_pack<<<dim3(16, 1, 16), dim3(64, 4), 0, stream>>>(d_in[3], Wqkv_t + 1048576,  65536, 65536, 1024, 64, &flags[3]);
  transpose_pack<<<dim3(16, 1, 16), dim3(64, 4), 0, stream>>>(d_in[5], Wqkv_t + 2097152,  65536, 65536, 1024, 64, &flags[5]);
  transpose_pack<<<dim3(16, 16, 1), dim3(64, 4), 0, stream>>>(d_in[7],  Wo_t, 0, 0, 1024, 1024, &flags[7]);
  transpose_pack<<<dim3(16, 64, 1), dim3(64, 4), 0, stream>>>(d_in[11], W1_t, 0, 0, 1024, 4096, &flags[11]);
  transpose_pack<<<dim3(64, 16, 1), dim3(64, 4), 0, stream>>>(d_in[13], W2_t, 0, 0, 4096, 1024, &flags[13]);

  // ---- small vectors: one launch ----
  CvtTab ct;
  const int srcs[10]   = {2, 4, 6, 8, 9, 10, 12, 14, 15, 16};
  const int offs[10]   = {0, 1024, 2048, 3072, 4096, 5120, 6144, 10240, 11264, 12288};
  const int lens[10]   = {1024, 1024, 1024, 1024, 1024, 1024, 4096, 1024, 1024, 1024};
  for (int e = 0; e < 10; e++) { ct.p[e] = d_in[srcs[e]]; ct.flagidx[e] = srcs[e]; ct.dstoff[e] = offs[e]; ct.n[e] = lens[e]; }
  cvt_small<<<dim3(10), 256, 0, stream>>>(ct, svec, flags);

  // ---- src -> bf16 ----
  cvt_src<<<dim3(TOK * 1024 / (256 * 8)), 256, 0, stream>>>(d_in[0], src_bf, &flags[0]);

  // qkv = src @ Wqkv + b           [8192,3072]
  gemm_bt<<<dim3(64, 24), 256, 0, stream>>>(src_bf, Wqkv_t, bqkv, qkv, TOK, 3072, 1024, 0);
  // attention                       [8192,1024]
  attn_fwd<<<dim3(16, 128), 256, 0, stream>>>(qkv, attnb);
  // proj = attn @ Wo + bo
  gemm_bt<<<dim3(64, 8), 256, 0, stream>>>(attnb, Wo_t, bo_c, proj, TOK, 1024, 1024, 0);
  // x = LN(src + proj)
  add_ln<<<dim3(TOK), 256, 0, stream>>>(src_bf, proj, g1_c, be1_c, x);
  // FF: h1 = relu(x@W1+b1); f2 = h1@W2+b2, chunked by CH rows
  for (int c = 0; c < TOK / CH; c++) {
    const u16* xc = x + (size_t)c * CH * 1024;
    u16* f2c = f2 + (size_t)c * CH * 1024;
    gemm_bt<<<dim3(CH / 128, 32), 256, 0, stream>>>(xc, W1_t, b1_c, h1, CH, 4096, 1024, 1);
    gemm_bt<<<dim3(CH / 128, 8), 256, 0, stream>>>(h1, W2_t, b2_c, f2c, CH, 1024, 4096, 0);
  }
  // out = LN(x + f2), stored in src's container dtype
  add_ln_out<<<dim3(TOK), 256, 0, stream>>>(x, f2, g2_c, be2_c, d_out, &flags[0]);
  diag_mixed<<<1, 1, 0, stream>>>(flags, d_out);
}

// Round 8
// 623.796 us; speedup vs baseline: 1.2217x; 1.1170x over previous
//
#include <hip/hip_runtime.h>

// B=8 S=1024 D=1024 H=16 DK=64 F=4096 -- fp32 containers (bf16-valued), detected per-tensor
#define Bq 8
#define Sq 1024
#define Dq 1024
#define Hq 16
#define DKq 64
#define Fq 4096
#define TOK (Bq*Sq)   // 8192

typedef unsigned short u16;
typedef unsigned int u32;
typedef __bf16 bf16x8 __attribute__((ext_vector_type(8)));
typedef float  f32x4  __attribute__((ext_vector_type(4)));

__device__ __forceinline__ float bf2f(u16 u) {
  u32 x = ((u32)u) << 16;
  float f; __builtin_memcpy(&f, &x, 4); return f;
}
__device__ __forceinline__ u16 f2bf(float f) {
  u32 u; __builtin_memcpy(&u, &f, 4);
  u += 0x7fffu + ((u >> 16) & 1u);
  return (u16)(u >> 16);
}
// async global->LDS, 16B/lane; LDS dest = wave-uniform base + lane*16
__device__ __forceinline__ void async16(const u16* g, u16* l) {
  __builtin_amdgcn_global_load_lds(
      (__attribute__((address_space(1))) void*)(g),
      (__attribute__((address_space(3))) void*)(l), 16, 0, 0);
}
__device__ __forceinline__ u16 load_in(const void* p, long idx, u32 fp32) {
  return fp32 ? f2bf(((const float*)p)[idx]) : ((const u16*)p)[idx];
}

// ---------------- dtype detection: one launch, 17 blocks ----------------
struct InTab { const void* p[17]; int n[17]; };

__global__ void detect_all(InTab tab, u32* flags) {
  __shared__ int sh[3][256];
  int bi = blockIdx.x;
  const u16* buf = (const u16*)tab.p[bi];
  long n = tab.n[bi];
  long m = n < 65536 ? n : 65536;
  int t = threadIdx.x;
  int nanpat = 0, evz = 0, oddnz = 0;
  for (long i = t; i < m; i += 256) {
    u16 v = buf[i];
    if ((v & 0x7F80u) == 0x7F80u) nanpat++;
    if ((i & 1) == 0) { if (v == 0) evz++; }
    else { if (v != 0) oddnz++; }
  }
  sh[0][t] = nanpat; sh[1][t] = evz; sh[2][t] = oddnz;
  __syncthreads();
  for (int s = 128; s > 0; s >>= 1) {
    if (t < s) { sh[0][t] += sh[0][t+s]; sh[1][t] += sh[1][t+s]; sh[2][t] += sh[2][t+s]; }
    __syncthreads();
  }
  if (t == 0) {
    long half = m / 2;
    bool fp32 = (sh[0][0] > 8) ||
                (sh[1][0] > (half * 9) / 10 && sh[2][0] > (half * 9) / 10);
    flags[bi] = fp32 ? 1u : 0u;
  }
}

__global__ void diag_ws_too_small(u16* out, float code) { out[0] = f2bf(code); }

__global__ void diag_mixed(const u32* flags, void* out) {
  u32 a = flags[0];
  if (flags[1] != a || flags[7] != a || flags[11] != a || flags[13] != a) {
    if (a) ((float*)out)[0] = 3000.0f;
    else ((u16*)out)[0] = f2bf(3000.0f);
  }
}

// ---------------- batched LDS-tiled transpose pack (single launch) ----------------
// 3072 tile-jobs of 64x64: [0,768) Wq/Wk/Wv slices, [768,1024) Wo, [1024,2048) W1, [2048,3072) W2
__global__ __launch_bounds__(256) void pack_all(const void* __restrict__ Wq,
                                                const void* __restrict__ Wk,
                                                const void* __restrict__ Wv,
                                                const void* __restrict__ Wo,
                                                const void* __restrict__ W1,
                                                const void* __restrict__ W2,
                                                u16* __restrict__ Wqkv_t,
                                                u16* __restrict__ Wo_t,
                                                u16* __restrict__ W1_t,
                                                u16* __restrict__ W2_t,
                                                const u32* __restrict__ flags) {
  int id = blockIdx.x;
  const void* in; u16* out; u32 f; int R, C; long zin; int r0, c0;
  if (id < 768) {            // Wq/Wk/Wv: [16 h][1024 d][64 dk] -> [h*64+dk][d]
    int w = id >> 8, t = id & 255;
    int z = t >> 4, xt = t & 15;
    in = (w == 0) ? Wq : ((w == 1) ? Wk : Wv);
    f = flags[(w == 0) ? 1 : ((w == 1) ? 3 : 5)];
    R = 1024; C = 64;
    zin = (long)z * 65536;
    out = Wqkv_t + (long)w * 1048576 + (long)z * 65536;
    r0 = xt * 64; c0 = 0;
  } else if (id < 1024) {    // Wo [1024][1024]
    int t = id - 768; int xt = t & 15, yt = t >> 4;
    in = Wo; f = flags[7]; R = 1024; C = 1024; zin = 0; out = Wo_t;
    r0 = xt * 64; c0 = yt * 64;
  } else if (id < 2048) {    // W1 [1024][4096]
    int t = id - 1024; int xt = t & 15, yt = t >> 4;
    in = W1; f = flags[11]; R = 1024; C = 4096; zin = 0; out = W1_t;
    r0 = xt * 64; c0 = yt * 64;
  } else {                   // W2 [4096][1024]
    int t = id - 2048; int xt = t & 63, yt = t >> 6;
    in = W2; f = flags[13]; R = 4096; C = 1024; zin = 0; out = W2_t;
    r0 = xt * 64; c0 = yt * 64;
  }
  __shared__ u16 tile[64][65];
  int tx = threadIdx.x & 63, ty = threadIdx.x >> 6;
#pragma unroll
  for (int it = 0; it < 16; it++) {
    int row = it * 4 + ty;
    tile[row][tx] = load_in(in, zin + (long)(r0 + row) * C + (c0 + tx), f);
  }
  __syncthreads();
#pragma unroll
  for (int it = 0; it < 16; it++) {
    int cc = it * 4 + ty;
    out[(long)(c0 + cc) * R + r0 + tx] = tile[tx][cc];
  }
}

// ---------------- merged small-vector cvt ----------------
struct CvtTab { const void* p[10]; int flagidx[10]; int dstoff[10]; int n[10]; };
__global__ void cvt_small(CvtTab tab, u16* __restrict__ dst, const u32* __restrict__ flags) {
  int e = blockIdx.x;
  u32 f = flags[tab.flagidx[e]];
  const void* p = tab.p[e];
  int n = tab.n[e], o = tab.dstoff[e];
  for (int i = threadIdx.x; i < n; i += 256) dst[o + i] = load_in(p, i, f);
}

// ---------------- vectorized src cvt (8 elems/thread) ----------------
__global__ __launch_bounds__(256) void cvt_src(const void* __restrict__ in,
                                               u16* __restrict__ out,
                                               const u32* __restrict__ flag) {
  u32 f = *flag;
  long i8 = ((long)blockIdx.x * 256 + threadIdx.x) * 8;
  if (f) {
    const float4* f4 = (const float4*)((const float*)in + i8);
    float4 a = f4[0], b = f4[1];
    u16 v[8] = {f2bf(a.x), f2bf(a.y), f2bf(a.z), f2bf(a.w),
                f2bf(b.x), f2bf(b.y), f2bf(b.z), f2bf(b.w)};
    *(uint4*)(out + i8) = *(const uint4*)v;
  } else {
    *(uint4*)(out + i8) = *(const uint4*)((const u16*)in + i8);
  }
}

// ---------------- GEMM: C[M,N] = A[M,K] @ Bt[N,K]^T + bias, optional ReLU --------
// 128x128 tile, BK=32, double-buffered LDS, ONE barrier per K-step (was 2):
// staged loads get a full MFMA phase in flight before their drain barrier.
__global__ __launch_bounds__(256) void gemm_bt(const u16* __restrict__ A,
                                               const u16* __restrict__ Bt,
                                               const u16* __restrict__ bias,
                                               u16* __restrict__ C,
                                               int M, int N, int K, int act) {
  __shared__ alignas(16) u16 sA[2][128 * 32];
  __shared__ alignas(16) u16 sB[2][128 * 32];
  const int tid = threadIdx.x;
  const int wv = tid >> 6, lane = tid & 63;
  const int m16 = lane & 15, quad = lane >> 4;
  const long bm = (long)blockIdx.x * 128;
  const long bn = (long)blockIdx.y * 128;
  const int wm = (wv >> 1) * 64, wn = (wv & 1) * 64;

  f32x4 acc[4][4];
#pragma unroll
  for (int i = 0; i < 4; i++)
#pragma unroll
    for (int j = 0; j < 4; j++) acc[i][j] = (f32x4){0.f, 0.f, 0.f, 0.f};

  const int row_s = tid >> 2;          // 0..63
  const int col_s = (tid & 3) * 8;
  const u16* gA0 = A + (bm + row_s) * (long)K + col_s;
  const u16* gA1 = gA0 + 64 * (long)K;
  const u16* gB0 = Bt + (bn + row_s) * (long)K + col_s;
  const u16* gB1 = gB0 + 64 * (long)K;

  auto stage = [&](int p, int k) {
    async16(gA0 + k, &sA[p][wv * 512]);
    async16(gA1 + k, &sA[p][2048 + wv * 512]);
    async16(gB0 + k, &sB[p][wv * 512]);
    async16(gB1 + k, &sB[p][2048 + wv * 512]);
  };
  auto compute = [&](int p) {
    bf16x8 af[4], bf_[4];
#pragma unroll
    for (int mi = 0; mi < 4; mi++)
      af[mi] = *(const bf16x8*)&sA[p][(wm + mi * 16 + m16) * 32 + quad * 8];
#pragma unroll
    for (int ni = 0; ni < 4; ni++)
      bf_[ni] = *(const bf16x8*)&sB[p][(wn + ni * 16 + m16) * 32 + quad * 8];
#pragma unroll
    for (int mi = 0; mi < 4; mi++)
#pragma unroll
      for (int ni = 0; ni < 4; ni++)
        acc[mi][ni] = __builtin_amdgcn_mfma_f32_16x16x32_bf16(af[mi], bf_[ni], acc[mi][ni], 0, 0, 0);
  };

  stage(0, 0);
  for (int k0 = 0; k0 < K; k0 += 64) {   // K is a multiple of 64 (1024/4096)
    __syncthreads();                     // drains stage(0,k0); protects buf1 from prev iter
    if (k0 + 32 < K) stage(1, k0 + 32);
    compute(0);
    __syncthreads();                     // drains stage(1); protects buf0
    if (k0 + 64 < K) stage(0, k0 + 64);
    compute(1);
  }

  float bv4[4];
#pragma unroll
  for (int ni = 0; ni < 4; ni++) bv4[ni] = bf2f(bias[bn + wn + ni * 16 + m16]);

#pragma unroll
  for (int mi = 0; mi < 4; mi++) {
#pragma unroll
    for (int ni = 0; ni < 4; ni++) {
      long col = bn + wn + ni * 16 + m16;
#pragma unroll
      for (int r = 0; r < 4; r++) {
        long row = bm + wm + mi * 16 + quad * 4 + r;
        float v = acc[mi][ni][r] + bv4[ni];
        if (act) v = fmaxf(v, 0.f);
        C[row * N + col] = f2bf(v);
      }
    }
  }
}

// ---------------- flash attention, S^T = K Q^T layout ----------------
// grid (B*H, S/64): bh = blockIdx.x so all 16 q-tiles of one (b,h) share an XCD
// (id%8 heuristic) -> K/V served from that XCD's L2. (256,3): no spill (<=170 VGPR).
__global__ __launch_bounds__(256, 3) void attn_fwd(const u16* __restrict__ qkv,
                                                   u16* __restrict__ attnO) {
  __shared__ alignas(16) u16 sQP[4608];  // Q [64][72]; later per-wave P[16][72] at wv*1152
  __shared__ alignas(16) u16 sK[4608];   // [key][dk] stride 72
  __shared__ alignas(16) u16 sVt[4608];  // [dk][key] stride 72
  const int tid = threadIdx.x;
  const int bh = blockIdx.x;
  const int qt = blockIdx.y;
  const int b = bh >> 4, h = bh & 15;
  const int wv = tid >> 6, lane = tid & 63;
  const int m16 = lane & 15, quad = lane >> 4;
  const int toct = tid & 7;
  const int r_0 = tid >> 3;              // staging row (0..31)
  const int d_0 = (tid & 7) * 8;         // staging dk offset

  // stage Q [64 q][64 dk], pre-scaled by 1/sqrt(DK)=0.125 (exact, power of 2)
#pragma unroll
  for (int i = 0; i < 2; i++) {
    int r = i * 32 + r_0;
    const u16* g = qkv + ((long)(b * Sq + qt * 64 + r)) * 3072 + h * 64 + d_0;
    uint4 raw = *(const uint4*)g;
    const u16* pv = (const u16*)&raw;
    u16 t[8];
#pragma unroll
    for (int j = 0; j < 8; j++) t[j] = f2bf(bf2f(pv[j]) * 0.125f);
    *(uint4*)&sQP[r * 72 + d_0] = *(const uint4*)t;
  }
  __syncthreads();
  bf16x8 aq0 = *(const bf16x8*)&sQP[(wv * 16 + m16) * 72 + quad * 8];
  bf16x8 aq1 = *(const bf16x8*)&sQP[(wv * 16 + m16) * 72 + 32 + quad * 8];

  f32x4 oacc[4];
#pragma unroll
  for (int ni = 0; ni < 4; ni++) oacc[ni] = (f32x4){0.f, 0.f, 0.f, 0.f};
  float mrun = -1e30f, lrun = 0.f;

  const u16* gK0 = qkv + (long)(b * Sq + r_0) * 3072 + h * 64 + d_0 + 1024;
  const u16* gK1 = gK0 + 32 * 3072;
  const long step = 64 * 3072;

  uint4 rk0 = *(const uint4*)gK0;
  uint4 rk1 = *(const uint4*)gK1;
  uint4 rv0 = *(const uint4*)(gK0 + 1024);
  uint4 rv1 = *(const uint4*)(gK1 + 1024);

  for (int kt = 0; kt < 16; kt++) {
    __syncthreads();   // previous iteration's K/Vt/P reads done
    *(uint4*)&sK[r_0 * 72 + d_0] = rk0;
    *(uint4*)&sK[(r_0 + 32) * 72 + d_0] = rk1;
    {
      const u16* pv0 = (const u16*)&rv0;
      const u16* pv1 = (const u16*)&rv1;
#pragma unroll
      for (int j = 0; j < 8; j++) {       // V transpose, octet-rotated (2-way = free)
        int jr = (j + toct) & 7;
        sVt[(d_0 + jr) * 72 + r_0] = pv0[jr];
        sVt[(d_0 + jr) * 72 + r_0 + 32] = pv1[jr];
      }
    }
    __syncthreads();   // tiles published

    if (kt < 15) {     // prefetch next K/V
      const u16* nK0 = gK0 + (long)(kt + 1) * step;
      const u16* nK1 = gK1 + (long)(kt + 1) * step;
      rk0 = *(const uint4*)nK0;
      rk1 = *(const uint4*)nK1;
      rv0 = *(const uint4*)(nK0 + 1024);
      rv1 = *(const uint4*)(nK1 + 1024);
    }

    // S^T[key][q] = K Q^T : st[ni][r] = S^T[ni*16+quad*4+r][m16]
    f32x4 st[4];
#pragma unroll
    for (int ni = 0; ni < 4; ni++) st[ni] = (f32x4){0.f, 0.f, 0.f, 0.f};
#pragma unroll
    for (int ni = 0; ni < 4; ni++) {
      bf16x8 bk0 = *(const bf16x8*)&sK[(ni * 16 + m16) * 72 + quad * 8];
      bf16x8 bk1 = *(const bf16x8*)&sK[(ni * 16 + m16) * 72 + 32 + quad * 8];
      st[ni] = __builtin_amdgcn_mfma_f32_16x16x32_bf16(bk0, aq0, st[ni], 0, 0, 0);
      st[ni] = __builtin_amdgcn_mfma_f32_16x16x32_bf16(bk1, aq1, st[ni], 0, 0, 0);
    }

    // online softmax: all 16 st values share q=m16 -> scalar stats per lane
    float pmax = st[0][0];
#pragma unroll
    for (int ni = 0; ni < 4; ni++)
#pragma unroll
      for (int r = 0; r < 4; r++) pmax = fmaxf(pmax, st[ni][r]);
    pmax = fmaxf(pmax, __shfl_xor(pmax, 16));
    pmax = fmaxf(pmax, __shfl_xor(pmax, 32));
    float mnew = fmaxf(mrun, pmax);
    float alpha = __expf(mrun - mnew);
    mrun = mnew;

    // exp + bf16-pack + P store fused (no ps[][] live range -> no spill)
    u16* sPw = &sQP[wv * 1152];
    float rs = 0.f;
#pragma unroll
    for (int ni = 0; ni < 4; ni++) {
      u16 t4[4];
#pragma unroll
      for (int r = 0; r < 4; r++) {
        float p = __expf(st[ni][r] - mnew);
        rs += p;
        t4[r] = f2bf(p);
      }
      *(uint2*)&sPw[m16 * 72 + ni * 16 + quad * 4] = *(const uint2*)t4;
    }
    rs += __shfl_xor(rs, 16);
    rs += __shfl_xor(rs, 32);
    lrun = lrun * alpha + rs;
#pragma unroll
    for (int ni = 0; ni < 4; ni++)
#pragma unroll
      for (int r = 0; r < 4; r++) oacc[ni][r] *= alpha;

    bf16x8 pb0 = *(const bf16x8*)&sPw[m16 * 72 + quad * 8];
    bf16x8 pb1 = *(const bf16x8*)&sPw[m16 * 72 + 32 + quad * 8];

    // O^T += V^T P^T
#pragma unroll
    for (int ni = 0; ni < 4; ni++) {
      bf16x8 av0 = *(const bf16x8*)&sVt[(ni * 16 + m16) * 72 + quad * 8];
      bf16x8 av1 = *(const bf16x8*)&sVt[(ni * 16 + m16) * 72 + 32 + quad * 8];
      oacc[ni] = __builtin_amdgcn_mfma_f32_16x16x32_bf16(av0, pb0, oacc[ni], 0, 0, 0);
      oacc[ni] = __builtin_amdgcn_mfma_f32_16x16x32_bf16(av1, pb1, oacc[ni], 0, 0, 0);
    }
  }

  float rl = 1.f / lrun;
  long row = (long)(b * Sq + qt * 64 + wv * 16 + m16);
#pragma unroll
  for (int ni = 0; ni < 4; ni++) {
    u16 t[4];
#pragma unroll
    for (int r = 0; r < 4; r++) t[r] = f2bf(oacc[ni][r] * rl);
    *(uint2*)&attnO[row * 1024 + h * 64 + ni * 16 + quad * 4] = *(const uint2*)t;
  }
}

// ---------------- add + LayerNorm (bf16 out, internal) ----------------
__global__ __launch_bounds__(256) void add_ln(const u16* __restrict__ X,
                                              const u16* __restrict__ Y,
                                              const u16* __restrict__ g,
                                              const u16* __restrict__ be,
                                              u16* __restrict__ out) {
  const int row = blockIdx.x;
  const int t = threadIdx.x;
  const long base = (long)row * Dq;
  float v[4]; float s = 0.f, ss = 0.f;
#pragma unroll
  for (int i = 0; i < 4; i++) {
    int idx = i * 256 + t;
    float x = bf2f(X[base + idx]) + bf2f(Y[base + idx]);
    v[i] = x; s += x; ss += x * x;
  }
#pragma unroll
  for (int off = 32; off > 0; off >>= 1) { s += __shfl_down(s, off); ss += __shfl_down(ss, off); }
  __shared__ float red[8];
  int wv = t >> 6, ln = t & 63;
  if (ln == 0) { red[wv] = s; red[4 + wv] = ss; }
  __syncthreads();
  s = red[0] + red[1] + red[2] + red[3];
  ss = red[4] + red[5] + red[6] + red[7];
  float mean = s * (1.f / Dq);
  float var = ss * (1.f / Dq) - mean * mean;
  float rstd = rsqrtf(var + 1e-5f);
#pragma unroll
  for (int i = 0; i < 4; i++) {
    int idx = i * 256 + t;
    float o = (v[i] - mean) * rstd * bf2f(g[idx]) + bf2f(be[idx]);
    out[base + idx] = f2bf(o);
  }
}

// ---------------- final add + LayerNorm, dual-dtype store ----------------
__global__ __launch_bounds__(256) void add_ln_out(const u16* __restrict__ X,
                                                  const u16* __restrict__ Y,
                                                  const u16* __restrict__ g,
                                                  const u16* __restrict__ be,
                                                  void* __restrict__ out,
                                                  const u32* __restrict__ outflag) {
  const u32 fp32 = *outflag;
  const int row = blockIdx.x;
  const int t = threadIdx.x;
  const long base = (long)row * Dq;
  float v[4]; float s = 0.f, ss = 0.f;
#pragma unroll
  for (int i = 0; i < 4; i++) {
    int idx = i * 256 + t;
    float x = bf2f(X[base + idx]) + bf2f(Y[base + idx]);
    v[i] = x; s += x; ss += x * x;
  }
#pragma unroll
  for (int off = 32; off > 0; off >>= 1) { s += __shfl_down(s, off); ss += __shfl_down(ss, off); }
  __shared__ float red[8];
  int wv = t >> 6, ln = t & 63;
  if (ln == 0) { red[wv] = s; red[4 + wv] = ss; }
  __syncthreads();
  s = red[0] + red[1] + red[2] + red[3];
  ss = red[4] + red[5] + red[6] + red[7];
  float mean = s * (1.f / Dq);
  float var = ss * (1.f / Dq) - mean * mean;
  float rstd = rsqrtf(var + 1e-5f);
#pragma unroll
  for (int i = 0; i < 4; i++) {
    int idx = i * 256 + t;
    float o = (v[i] - mean) * rstd * bf2f(g[idx]) + bf2f(be[idx]);
    if (fp32) ((float*)out)[base + idx] = o;
    else ((u16*)out)[base + idx] = f2bf(o);
  }
}

extern "C" void kernel_launch(void* const* d_in, const int* in_sizes, int n_in,
                              void* d_out, int out_size, void* d_ws, size_t ws_size,
                              hipStream_t stream) {
  char* ws = (char*)d_ws;
  size_t off = 0;
  auto alloc = [&](size_t bytes) {
    void* p = ws + off;
    off += (bytes + 255) & ~(size_t)255;
    return p;
  };
  u32* flags  = (u32*)alloc(32 * 4);
  u16* Wqkv_t = (u16*)alloc((size_t)3072 * 1024 * 2);   // 6 MB
  u16* Wo_t   = (u16*)alloc((size_t)1024 * 1024 * 2);   // 2 MB
  u16* W1_t   = (u16*)alloc((size_t)4096 * 1024 * 2);   // 8 MB
  u16* W2_t   = (u16*)alloc((size_t)1024 * 4096 * 2);   // 8 MB
  u16* svec   = (u16*)alloc((size_t)13312 * 2);         // all small vectors
  u16* src_bf = (u16*)alloc((size_t)TOK * 1024 * 2);    // 16 MB
  u16* regA   = (u16*)alloc((size_t)TOK * 4096 * 2);    // 64 MB
  size_t need_chunk2 = off;                              // h1(32MB) fits inside regA
  size_t need_full   = off + (size_t)TOK * 4096 * 2 / 2; // +32MB so h1(64MB) spans past regA

  u16* outw = (u16*)d_out;
  int CH;  // rows per FF chunk
  if (ws_size >= need_full) { CH = 8192; (void)alloc((size_t)32 << 20); }
  else if (ws_size >= need_chunk2) CH = 4096;
  else if (ws_size >= need_chunk2 - ((size_t)16 << 20)) CH = 2048;
  else {
    diag_ws_too_small<<<1, 1, 0, stream>>>(outw, 8000.0f + (float)(ws_size >> 20));
    return;
  }

  u16* qkv   = regA;                          // [0,48) MB
  u16* attnb = regA + (size_t)TOK * 3072;     // [48,64) MB
  u16* proj  = regA;                          // [0,16)  after qkv dead
  u16* x     = regA + (size_t)TOK * 1024;     // [16,32)
  u16* h1    = regA + (size_t)TOK * 2048;     // [32,..) CH*4096*2 bytes
  u16* f2    = src_bf;                        // src_bf dead after x computed

  u16* bqkv = svec + 0;      // 3072
  u16* bo_c = svec + 3072;
  u16* g1_c = svec + 4096;
  u16* be1_c = svec + 5120;
  u16* b1_c = svec + 6144;   // 4096
  u16* b2_c = svec + 10240;
  u16* g2_c = svec + 11264;
  u16* be2_c = svec + 12288;

  // ---- dtype detection ----
  InTab itab;
  for (int i = 0; i < 17; i++) { itab.p[i] = d_in[i]; itab.n[i] = in_sizes[i]; }
  detect_all<<<dim3(17), 256, 0, stream>>>(itab, flags);

  // ---- all weight transposes in one launch ----
  pack_all<<<dim3(3072), 256, 0, stream>>>(d_in[1], d_in[3], d_in[5], d_in[7], d_in[11], d_in[13],
                                           Wqkv_t, Wo_t, W1_t, W2_t, flags);

  // ---- small vectors ----
  CvtTab ct;
  const int srcs[10] = {2, 4, 6, 8, 9, 10, 12, 14, 15, 16};
  const int offs[10] = {0, 1024, 2048, 3072, 4096, 5120, 6144, 10240, 11264, 12288};
  const int lens[10] = {1024, 1024, 1024, 1024, 1024, 1024, 4096, 1024, 1024, 1024};
  for (int e = 0; e < 10; e++) { ct.p[e] = d_in[srcs[e]]; ct.flagidx[e] = srcs[e]; ct.dstoff[e] = offs[e]; ct.n[e] = lens[e]; }
  cvt_small<<<dim3(10), 256, 0, stream>>>(ct, svec, flags);

  // ---- src -> bf16 ----
  cvt_src<<<dim3(TOK * 1024 / (256 * 8)), 256, 0, stream>>>(d_in[0], src_bf, &flags[0]);

  // qkv = src @ Wqkv + b           [8192,3072]
  gemm_bt<<<dim3(64, 24), 256, 0, stream>>>(src_bf, Wqkv_t, bqkv, qkv, TOK, 3072, 1024, 0);
  // attention                       [8192,1024]  (grid: bh-major for XCD locality)
  attn_fwd<<<dim3(128, 16), 256, 0, stream>>>(qkv, attnb);
  // proj = attn @ Wo + bo
  gemm_bt<<<dim3(64, 8), 256, 0, stream>>>(attnb, Wo_t, bo_c, proj, TOK, 1024, 1024, 0);
  // x = LN(src + proj)
  add_ln<<<dim3(TOK), 256, 0, stream>>>(src_bf, proj, g1_c, be1_c, x);
  // FF chunked by CH rows
  for (int c = 0; c < TOK / CH; c++) {
    const u16* xc = x + (size_t)c * CH * 1024;
    u16* f2c = f2 + (size_t)c * CH * 1024;
    gemm_bt<<<dim3(CH / 128, 32), 256, 0, stream>>>(xc, W1_t, b1_c, h1, CH, 4096, 1024, 1);
    gemm_bt<<<dim3(CH / 128, 8), 256, 0, stream>>>(h1, W2_t, b2_c, f2c, CH, 1024, 4096, 0);
  }
  // out = LN(x + f2), stored in src's container dtype
  add_ln_out<<<dim3(TOK), 256, 0, stream>>>(x, f2, g2_c, be2_c, d_out, &flags[0]);
  diag_mixed<<<1, 1, 0, stream>>>(flags, d_out);
}